// Round 6
// baseline (697.184 us; speedup 1.0000x reference)
//
#include <hip/hip_runtime.h>
#include <hip/hip_bf16.h>
#include <math.h>

// ReformerAttention (LSH attention) on MI355X.
// B=4 T=4096 HID=768 H=12 D=64 n_hashes=2 n_buckets=32 bucket=128.
// R6: k_bucket register-prefetch + BK=32 (bit-identical accumulation order);
//     k_norm fused into k_attn K-gather (bit-identical sum order).
//
// Workspace layout (bytes), peak 103,809,280:
//   0           flag   256
//   256         stick  u16[48][8192]        786,432
//   786,688     lse_r  f32[48*2][4096]    1,572,864
//   2,359,552   (unused; was nk)            786,432
//   3,145,984   qk     bf16[48][4096][64] 25,165,824   (later tmp)
//   28,311,808  v      bf16[48][4096][64] 25,165,824   (later attn)
//   53,477,632  o_r    bf16[96][4096][64] 50,331,648
//   overlays inside o_r (dead before k_attn): WrotT/cls/Wqkb/Wvb/Xb
//   after k_combine: Wtob/Wob

typedef __attribute__((ext_vector_type(8))) short bf16x8;
typedef __attribute__((ext_vector_type(4))) float f32x4;

__device__ __forceinline__ float bf_lo(unsigned int w) { return __uint_as_float(w << 16); }
__device__ __forceinline__ float bf_hi(unsigned int w) { return __uint_as_float(w & 0xffff0000u); }
__device__ __forceinline__ float load_in(const void* p, size_t i, bool f32) {
  return f32 ? ((const float*)p)[i]
             : __bfloat162float(((const __hip_bfloat16*)p)[i]);
}
__device__ __forceinline__ unsigned short f2bf(float x) {
  __hip_bfloat16 h = __float2bfloat16(x);
  return *reinterpret_cast<unsigned short*>(&h);
}
__device__ __forceinline__ float bf2f(unsigned short u) { return __uint_as_float(((unsigned int)u) << 16); }

// ---------------------------------------------------------------- dtype detect
__global__ void k_detect(const unsigned int* __restrict__ X, int* __restrict__ flag) {
  if (threadIdx.x == 0 && blockIdx.x == 0) {
    int vote = 0;
    for (int i = 0; i < 64; ++i) {
      unsigned int e = (X[i] >> 7) & 0xffu;
      vote += (e >= 100u && e <= 141u) ? 1 : 0;
    }
    *flag = (vote < 32) ? 1 : 0;   // 1 => inputs are f32
  }
}

// ---------------------------------------------------------------- convert input -> bf16
__global__ __launch_bounds__(256) void k_convert(
    const void* __restrict__ src, unsigned short* __restrict__ dst, int n,
    const int* __restrict__ flag) {
  const bool f32in = (*flag != 0);
  int i = blockIdx.x * 256 + threadIdx.x;
  if (i >= n) return;
  if (f32in) dst[i] = f2bf(((const float*)src)[i]);
  else       dst[i] = ((const unsigned short*)src)[i];
}

// ---------------------------------------------------------------- fold rotations (f64)
__global__ __launch_bounds__(256) void k_build_wrot(
    const void* __restrict__ Wqk, const void* __restrict__ rot,
    double* __restrict__ WrotT, const int* __restrict__ flag) {
  const bool f32in = (*flag != 0);
  int idx = blockIdx.x * 256 + threadIdx.x;
  if (idx >= 768 * 384) return;
  int row = idx % 384;
  int c   = idx / 384;
  int hh = row >> 5, hi = row & 31;
  double s = 0.0;
  for (int f = 0; f < 64; ++f) {
    double rv = (double)load_in(rot, f * 32 + hi, f32in);
    double wv = (double)load_in(Wqk, (size_t)(hh * 64 + f) * 768 + c, f32in);
    s = fma(rv, wv, s);
  }
  WrotT[(size_t)c * 384 + row] = s;
}

// ---------------------------------------------------------------- bucket scores (f64 GEMM) + argmax
// BM=128 BN=96 BK=32, 256 thr, thread tile 8x6, register prefetch of next
// k-tile (global latency overlaps the 32x48-FMA compute). k strictly
// ascending per accumulator => bit-identical to prior passing rounds.
__global__ __launch_bounds__(256, 2) void k_bucket(
    const void* __restrict__ X, const double* __restrict__ WrotT,
    unsigned char* __restrict__ cls, const int* __restrict__ flag) {
  const bool f32in = (*flag != 0);
  __shared__ double SH[7296];          // 58,368 B
  double* Xs = SH;                     // [32][130]
  double* Ws = SH + 4160;              // [32][98]
  double* Sc = SH;                     // [96][66]  (epilogue union)
  const int tid = threadIdx.x;
  const int M0 = blockIdx.x * 128;
  const int N0 = blockIdx.y * 96;
  const int tm = tid >> 4, tn = tid & 15;
  const int sr = tid >> 1, sh = tid & 1;     // X staging: row, 16-k half
  const int wk = tid >> 3, wg = tid & 7;     // W staging: k-row, 12-col group

  double acc[8][6];
  #pragma unroll
  for (int i = 0; i < 8; ++i)
    #pragma unroll
    for (int j = 0; j < 6; ++j) acc[i][j] = 0.0;

  uint4 px0, px1;                 // bf16 X prefetch
  float4 pf0, pf1, pf2, pf3;      // f32 X prefetch
  double pw[12];                  // W prefetch

  const size_t xrow = (size_t)(M0 + sr) * 768 + sh * 16;
  const double* wbase = WrotT + (size_t)wk * 384 + N0 + wg * 12;

  // prefetch tile 0
  if (f32in) {
    const float4* fp = (const float4*)((const float*)X + xrow);
    pf0 = fp[0]; pf1 = fp[1]; pf2 = fp[2]; pf3 = fp[3];
  } else {
    const uint4* up = (const uint4*)((const unsigned short*)X + xrow);
    px0 = up[0]; px1 = up[1];
  }
  #pragma unroll
  for (int e = 0; e < 12; ++e) pw[e] = wbase[e];

  for (int kt = 0; kt < 24; ++kt) {
    __syncthreads();
    {  // stage X regs -> Xs[k][m] (transposed, f64)
      double xv[16];
      if (f32in) {
        xv[0] = pf0.x; xv[1] = pf0.y; xv[2] = pf0.z; xv[3] = pf0.w;
        xv[4] = pf1.x; xv[5] = pf1.y; xv[6] = pf1.z; xv[7] = pf1.w;
        xv[8] = pf2.x; xv[9] = pf2.y; xv[10] = pf2.z; xv[11] = pf2.w;
        xv[12] = pf3.x; xv[13] = pf3.y; xv[14] = pf3.z; xv[15] = pf3.w;
      } else {
        xv[0] = (double)bf_lo(px0.x); xv[1] = (double)bf_hi(px0.x);
        xv[2] = (double)bf_lo(px0.y); xv[3] = (double)bf_hi(px0.y);
        xv[4] = (double)bf_lo(px0.z); xv[5] = (double)bf_hi(px0.z);
        xv[6] = (double)bf_lo(px0.w); xv[7] = (double)bf_hi(px0.w);
        xv[8] = (double)bf_lo(px1.x); xv[9] = (double)bf_hi(px1.x);
        xv[10] = (double)bf_lo(px1.y); xv[11] = (double)bf_hi(px1.y);
        xv[12] = (double)bf_lo(px1.z); xv[13] = (double)bf_hi(px1.z);
        xv[14] = (double)bf_lo(px1.w); xv[15] = (double)bf_hi(px1.w);
      }
      #pragma unroll
      for (int j = 0; j < 16; ++j) Xs[(sh * 16 + j) * 130 + sr] = xv[j];
      #pragma unroll
      for (int e = 0; e < 12; ++e) Ws[wk * 98 + wg * 12 + e] = pw[e];
    }
    __syncthreads();
    if (kt < 23) {   // prefetch next tile; latency hidden by the FMA loop
      int k0 = (kt + 1) * 32;
      if (f32in) {
        const float4* fp = (const float4*)((const float*)X + xrow + k0);
        pf0 = fp[0]; pf1 = fp[1]; pf2 = fp[2]; pf3 = fp[3];
      } else {
        const uint4* up = (const uint4*)((const unsigned short*)X + xrow + k0);
        px0 = up[0]; px1 = up[1];
      }
      const double* wp = wbase + (size_t)k0 * 384;
      #pragma unroll
      for (int e = 0; e < 12; ++e) pw[e] = wp[e];
    }
    #pragma unroll
    for (int k = 0; k < 32; ++k) {
      double a_[8], b_[6];
      #pragma unroll
      for (int i = 0; i < 8; ++i) a_[i] = Xs[k * 130 + tm * 8 + i];
      #pragma unroll
      for (int j = 0; j < 6; ++j) b_[j] = Ws[k * 98 + tn * 6 + j];
      #pragma unroll
      for (int i = 0; i < 8; ++i)
        #pragma unroll
        for (int j = 0; j < 6; ++j)
          acc[i][j] = fma(a_[i], b_[j], acc[i][j]);
    }
  }

  // epilogue: two 64-token chunks through Sc, then first-index-wins argmax
  #pragma unroll
  for (int chunk = 0; chunk < 2; ++chunk) {
    __syncthreads();
    if ((tm >> 3) == chunk) {
      #pragma unroll
      for (int tt = 0; tt < 8; ++tt)
        #pragma unroll
        for (int rr = 0; rr < 6; ++rr)
          Sc[(tn * 6 + rr) * 66 + (tm & 7) * 8 + tt] = acc[tt][rr];
    }
    __syncthreads();
    for (int task = tid; task < 384; task += 256) {
      int g = task >> 6, tok = task & 63;
      const double* s = &Sc[(g * 16) * 66 + tok];
      double mx = -1.0e300;
      #pragma unroll
      for (int i = 0; i < 16; ++i) {
        double a = s[i * 66];
        mx = fmax(mx, fmax(a, -a));
      }
      int amax = 0;
      #pragma unroll
      for (int i = 15; i >= 0; --i) if (-s[i * 66] == mx) amax = 16 + i;
      #pragma unroll
      for (int i = 15; i >= 0; --i) if (s[i * 66] == mx) amax = i;
      int m = M0 + chunk * 64 + tok;
      int b = m >> 12, t = m & 4095;
      int gg = blockIdx.y * 6 + g, hh = gg >> 1, h = gg & 1;
      cls[(size_t)(b * 12 + hh) * 8192 + h * 4096 + t] = (unsigned char)(h * 32 + amax);
    }
  }
}

// ---------------------------------------------------------------- parallel stable counting sort
__global__ __launch_bounds__(1024) void k_sort(
    const unsigned char* __restrict__ clsg,
    unsigned short* __restrict__ stick) {
  __shared__ unsigned short cntg[128 * 64];
  __shared__ int classbase[64];
  const int row = blockIdx.x;
  const int tid = threadIdx.x;
  const int wave = tid >> 6, lane = tid & 63;
  const unsigned char* cr = clsg + ((size_t)row << 13);

  for (int i = tid; i < 128 * 64 / 2; i += 1024) ((uint32_t*)cntg)[i] = 0;
  __syncthreads();

  unsigned char myc[8], myrank[8];
  const unsigned long long ltmask = (lane == 0) ? 0ull : (~0ull >> (64 - lane));
  #pragma unroll
  for (int chunk = 0; chunk < 8; ++chunk) {
    int g = chunk * 16 + wave;
    int j = g * 64 + lane;
    int c = cr[j];
    unsigned long long same = ~0ull;
    #pragma unroll
    for (int bit = 0; bit < 6; ++bit) {
      unsigned long long bm = __ballot((c >> bit) & 1);
      same &= ((c >> bit) & 1) ? bm : ~bm;
    }
    int rank = __popcll(same & ltmask);
    if (rank == 0) cntg[g * 64 + c] = (unsigned short)__popcll(same);
    myc[chunk] = (unsigned char)c;
    myrank[chunk] = (unsigned char)rank;
  }
  __syncthreads();
  if (tid < 64) {
    int run = 0;
    for (int g = 0; g < 128; ++g) {
      int t = cntg[g * 64 + tid];
      cntg[g * 64 + tid] = (unsigned short)run;
      run += t;
    }
    classbase[tid] = run;
  }
  __syncthreads();
  if (tid == 0) {
    int run = 0;
    for (int c = 0; c < 64; ++c) { int t = classbase[c]; classbase[c] = run; run += t; }
  }
  __syncthreads();
  unsigned short* out = stick + ((size_t)row << 13);
  #pragma unroll
  for (int chunk = 0; chunk < 8; ++chunk) {
    int g = chunk * 16 + wave;
    int j = g * 64 + lane;
    int c = myc[chunk];
    int pos = classbase[c] + cntg[g * 64 + c] + myrank[chunk];
    out[pos] = (unsigned short)j;
  }
}

// ---------------------------------------------------------------- MFMA GEMM, K=768
__global__ __launch_bounds__(256) void k_gemm_mfma(
    const unsigned short* __restrict__ A, const unsigned short* __restrict__ W,
    const void* __restrict__ bias, void* __restrict__ Cout,
    int layout, int out_ext, const int* __restrict__ flag) {
  const bool f32in = (*flag != 0);
  const bool oF32 = out_ext && f32in;
  __shared__ unsigned short As[128 * 40];
  __shared__ unsigned short Bs[128 * 40];
  const int tid = threadIdx.x;
  const int bm = blockIdx.x, bn = blockIdx.y;
  const int w = tid >> 6, lane = tid & 63;
  const int l15 = lane & 15, lq = lane >> 4;
  const int wm = (w >> 1) * 64, wn = (w & 1) * 64;
  const int r4 = tid >> 2, c4 = tid & 3;
  const unsigned short* Ag = A + (size_t)(bm * 128 + r4) * 768 + c4 * 8;
  const unsigned short* Bg = W + (size_t)(bn * 128 + r4) * 768 + c4 * 8;
  f32x4 acc[4][4];
  #pragma unroll
  for (int i = 0; i < 4; ++i)
    #pragma unroll
    for (int j = 0; j < 4; ++j) acc[i][j] = (f32x4){0.f, 0.f, 0.f, 0.f};
  uint4 pa0 = *(const uint4*)(Ag);
  uint4 pa1 = *(const uint4*)(Ag + 64 * 768);
  uint4 pb0 = *(const uint4*)(Bg);
  uint4 pb1 = *(const uint4*)(Bg + 64 * 768);
  for (int kt = 0; kt < 24; ++kt) {
    __syncthreads();
    *(uint4*)&As[r4 * 40 + c4 * 8] = pa0;
    *(uint4*)&As[(r4 + 64) * 40 + c4 * 8] = pa1;
    *(uint4*)&Bs[r4 * 40 + c4 * 8] = pb0;
    *(uint4*)&Bs[(r4 + 64) * 40 + c4 * 8] = pb1;
    __syncthreads();
    if (kt < 23) {
      int off = (kt + 1) * 32;
      pa0 = *(const uint4*)(Ag + off);
      pa1 = *(const uint4*)(Ag + 64 * 768 + off);
      pb0 = *(const uint4*)(Bg + off);
      pb1 = *(const uint4*)(Bg + 64 * 768 + off);
    }
    bf16x8 af[4], bfr[4];
    #pragma unroll
    for (int mt = 0; mt < 4; ++mt)
      af[mt] = *(const bf16x8*)&As[(wm + mt * 16 + l15) * 40 + lq * 8];
    #pragma unroll
    for (int nt = 0; nt < 4; ++nt)
      bfr[nt] = *(const bf16x8*)&Bs[(wn + nt * 16 + l15) * 40 + lq * 8];
    #pragma unroll
    for (int mt = 0; mt < 4; ++mt)
      #pragma unroll
      for (int nt = 0; nt < 4; ++nt)
        acc[mt][nt] = __builtin_amdgcn_mfma_f32_16x16x32_bf16(af[mt], bfr[nt], acc[mt][nt], 0, 0, 0);
  }
  #pragma unroll
  for (int mt = 0; mt < 4; ++mt) {
    #pragma unroll
    for (int nt = 0; nt < 4; ++nt) {
      #pragma unroll
      for (int reg = 0; reg < 4; ++reg) {
        int m = bm * 128 + wm + mt * 16 + lq * 4 + reg;
        int n = bn * 128 + wn + nt * 16 + l15;
        float val = acc[mt][nt][reg];
        if (bias != nullptr) val += load_in(bias, n, f32in);
        if (layout == 0) {
          size_t addr = (size_t)m * 768 + n;
          if (oF32) ((float*)Cout)[addr] = val;
          else      ((unsigned short*)Cout)[addr] = f2bf(val);
        } else {
          int b2 = m >> 12, t2 = m & 4095, hh = n >> 6, f = n & 63;
          ((unsigned short*)Cout)[((((size_t)(b2 * 12 + hh)) << 12) + t2) * 64 + f] = f2bf(val);
        }
      }
    }
  }
}

// ---------------------------------------------------------------- MFMA LSH attention (norms fused)
__global__ __launch_bounds__(256) void k_attn_mfma(
    const unsigned short* __restrict__ qk,
    const unsigned short* __restrict__ vv,
    const unsigned short* __restrict__ stick,
    const void* __restrict__ mask,
    unsigned short* __restrict__ o_r,
    float* __restrict__ lse_r,
    const int* __restrict__ flag) {
  const bool f32in = (*flag != 0);
  __shared__ unsigned short Qs[128 * 72];
  __shared__ unsigned short Ks[64 * 72];
  __shared__ unsigned short Vt[64 * 72];
  __shared__ unsigned short Ps[4 * 32 * 72];
  __shared__ unsigned short Tq[128];
  __shared__ unsigned short Tkv[64];
  __shared__ float Nkv[64];
  unsigned short* Vs = Ps;

  const int tid = threadIdx.x;
  const int bh = blockIdx.x >> 6;
  const int ci = blockIdx.x & 63;
  const int b  = bh / 12;
  const int prev = (ci + 63) & 63;
  const int w = tid >> 6, lane = tid & 63;
  const int l15 = lane & 15, lq = lane >> 4;
  const unsigned short* srow = stick + ((size_t)bh << 13);
  const int jrow = tid >> 3, cs = tid & 7;

  #pragma unroll
  for (int pass = 0; pass < 4; ++pass) {
    int r = jrow + pass * 32;
    int s = srow[ci * 128 + r];
    int t = s & 4095;
    uint4 qw = ((const uint4*)(qk + ((((size_t)bh << 12) + t) << 6)))[cs];
    *(uint4*)&Qs[r * 72 + cs * 8] = qw;
    if (cs == 0) {
      float mv = load_in(mask, b * 4096 + t, f32in);
      Tq[r] = (unsigned short)(s | ((mv != 0.0f) ? 0 : 0x8000));
    }
  }
  __syncthreads();

  unsigned short tqr[2][4];
  #pragma unroll
  for (int mt = 0; mt < 2; ++mt)
    #pragma unroll
    for (int reg = 0; reg < 4; ++reg)
      tqr[mt][reg] = Tq[w * 32 + mt * 16 + lq * 4 + reg];

  float m_run[2][4], l_run[2][4];
  f32x4 oacc[2][4];
  #pragma unroll
  for (int mt = 0; mt < 2; ++mt)
    #pragma unroll
    for (int reg = 0; reg < 4; ++reg) { m_run[mt][reg] = -3.0e38f; l_run[mt][reg] = 0.0f; }
  #pragma unroll
  for (int mt = 0; mt < 2; ++mt)
    #pragma unroll
    for (int nto = 0; nto < 4; ++nto) oacc[mt][nto] = (f32x4){0.f, 0.f, 0.f, 0.f};

  for (int kt = 0; kt < 4; ++kt) {
    __syncthreads();
    #pragma unroll
    for (int pass = 0; pass < 2; ++pass) {
      int j = jrow + pass * 32;
      int chunk = (kt < 2) ? ci : prev;
      int s = srow[chunk * 128 + (kt & 1) * 64 + j];
      int t = s & 4095;
      const uint4* kb = (const uint4*)(qk + ((((size_t)bh << 12) + t) << 6));
      uint4 kw = kb[cs];
      *(uint4*)&Ks[j * 72 + cs * 8] = kw;
      // fused key-norm: same element order + shuffle sequence as old k_norm
      float ss = 0.f, e;
      e = bf_lo(kw.x); ss += e * e;  e = bf_hi(kw.x); ss += e * e;
      e = bf_lo(kw.y); ss += e * e;  e = bf_hi(kw.y); ss += e * e;
      e = bf_lo(kw.z); ss += e * e;  e = bf_hi(kw.z); ss += e * e;
      e = bf_lo(kw.w); ss += e * e;  e = bf_hi(kw.w); ss += e * e;
      ss += __shfl_xor(ss, 1, 64);
      ss += __shfl_xor(ss, 2, 64);
      ss += __shfl_xor(ss, 4, 64);
      const uint4* vb = (const uint4*)(vv + ((((size_t)bh << 12) + t) << 6));
      int sw = (cs ^ (j & 7) ^ (j >> 3)) & 7;
      *(uint4*)&Vs[j * 72 + sw * 8] = vb[cs];
      if (cs == 0) {
        float mv = load_in(mask, b * 4096 + t, f32in);
        Tkv[j] = (unsigned short)(t | ((mv != 0.0f) ? 0 : 0x8000));
        Nkv[j] = (1.0f / fmaxf(sqrtf(ss), 1e-12f)) * 0.125f;
      }
    }
    __syncthreads();

    #pragma unroll
    for (int i = 0; i < 8; ++i) {
      int cp = w * 8 + i;
      int q8 = cp >> 2;
      int sw = (q8 ^ (lane & 7) ^ (lane >> 3)) & 7;
      uint32_t wv = *(const uint32_t*)&Vs[lane * 72 + sw * 8 + ((2 * cp) & 7)];
      Vt[(2 * cp) * 72 + lane]     = (unsigned short)(wv & 0xffff);
      Vt[(2 * cp + 1) * 72 + lane] = (unsigned short)(wv >> 16);
    }

    f32x4 sacc[2][4];
    #pragma unroll
    for (int mt = 0; mt < 2; ++mt)
      #pragma unroll
      for (int nt = 0; nt < 4; ++nt) sacc[mt][nt] = (f32x4){0.f, 0.f, 0.f, 0.f};
    #pragma unroll
    for (int ks = 0; ks < 2; ++ks) {
      bf16x8 af[2];
      #pragma unroll
      for (int mt = 0; mt < 2; ++mt)
        af[mt] = *(const bf16x8*)&Qs[(w * 32 + mt * 16 + l15) * 72 + ks * 32 + lq * 8];
      #pragma unroll
      for (int nt = 0; nt < 4; ++nt) {
        bf16x8 bfr = *(const bf16x8*)&Ks[(nt * 16 + l15) * 72 + ks * 32 + lq * 8];
        #pragma unroll
        for (int mt = 0; mt < 2; ++mt)
          sacc[mt][nt] = __builtin_amdgcn_mfma_f32_16x16x32_bf16(af[mt], bfr, sacc[mt][nt], 0, 0, 0);
      }
    }

    unsigned short tkc[4];
    float nkc[4];
    #pragma unroll
    for (int nt = 0; nt < 4; ++nt) {
      tkc[nt] = Tkv[nt * 16 + l15];
      nkc[nt] = Nkv[nt * 16 + l15];
    }
    float dv[2][4][4];
    #pragma unroll
    for (int mt = 0; mt < 2; ++mt)
      #pragma unroll
      for (int nt = 0; nt < 4; ++nt)
        #pragma unroll
        for (int reg = 0; reg < 4; ++reg) {
          float x = sacc[mt][nt][reg] * nkc[nt];
          unsigned short ts = tqr[mt][reg];
          if (((tkc[nt] | ts) & 0x8000) != 0) x = -1.0e9f;
          if (((tkc[nt] ^ ts) & 0x0fff) == 0) x = -5.0e4f;
          dv[mt][nt][reg] = x;
        }
    float mn[2][4], scv[2][4];
    #pragma unroll
    for (int mt = 0; mt < 2; ++mt)
      #pragma unroll
      for (int reg = 0; reg < 4; ++reg) {
        float rm = fmaxf(fmaxf(dv[mt][0][reg], dv[mt][1][reg]),
                         fmaxf(dv[mt][2][reg], dv[mt][3][reg]));
        rm = fmaxf(rm, __shfl_xor(rm, 1, 64));
        rm = fmaxf(rm, __shfl_xor(rm, 2, 64));
        rm = fmaxf(rm, __shfl_xor(rm, 4, 64));
        rm = fmaxf(rm, __shfl_xor(rm, 8, 64));
        float mnew = fmaxf(m_run[mt][reg], rm);
        scv[mt][reg] = __expf(m_run[mt][reg] - mnew);
        m_run[mt][reg] = mnew;
        mn[mt][reg] = mnew;
      }
    #pragma unroll
    for (int mt = 0; mt < 2; ++mt)
      #pragma unroll
      for (int nt = 0; nt < 4; ++nt)
        #pragma unroll
        for (int reg = 0; reg < 4; ++reg)
          dv[mt][nt][reg] = __expf(dv[mt][nt][reg] - mn[mt][reg]);
    #pragma unroll
    for (int mt = 0; mt < 2; ++mt)
      #pragma unroll
      for (int reg = 0; reg < 4; ++reg) {
        float rs = ((dv[mt][0][reg] + dv[mt][1][reg]) + (dv[mt][2][reg] + dv[mt][3][reg]));
        rs += __shfl_xor(rs, 1, 64);
        rs += __shfl_xor(rs, 2, 64);
        rs += __shfl_xor(rs, 4, 64);
        rs += __shfl_xor(rs, 8, 64);
        l_run[mt][reg] = l_run[mt][reg] * scv[mt][reg] + rs;
      }
    #pragma unroll
    for (int mt = 0; mt < 2; ++mt)
      #pragma unroll
      for (int nto = 0; nto < 4; ++nto)
        #pragma unroll
        for (int reg = 0; reg < 4; ++reg)
          oacc[mt][nto][reg] *= scv[mt][reg];

    __syncthreads();

    #pragma unroll
    for (int mt = 0; mt < 2; ++mt)
      #pragma unroll
      for (int nt = 0; nt < 4; ++nt)
        #pragma unroll
        for (int reg = 0; reg < 4; ++reg)
          Ps[w * 2304 + (mt * 16 + lq * 4 + reg) * 72 + nt * 16 + l15] = f2bf(dv[mt][nt][reg]);

    #pragma unroll
    for (int ks = 0; ks < 2; ++ks) {
      bf16x8 pf[2];
      #pragma unroll
      for (int mt = 0; mt < 2; ++mt)
        pf[mt] = *(const bf16x8*)&Ps[w * 2304 + (mt * 16 + l15) * 72 + ks * 32 + lq * 8];
      #pragma unroll
      for (int nto = 0; nto < 4; ++nto) {
        bf16x8 vf = *(const bf16x8*)&Vt[(nto * 16 + l15) * 72 + ks * 32 + lq * 8];
        #pragma unroll
        for (int mt = 0; mt < 2; ++mt)
          oacc[mt][nto] = __builtin_amdgcn_mfma_f32_16x16x32_bf16(pf[mt], vf, oacc[mt][nto], 0, 0, 0);
      }
    }
  }

  float invl[2][4];
  #pragma unroll
  for (int mt = 0; mt < 2; ++mt)
    #pragma unroll
    for (int reg = 0; reg < 4; ++reg) {
      float lr = l_run[mt][reg];
      invl[mt][reg] = 1.0f / lr;
      if (l15 == 0) {
        int Rr = w * 32 + mt * 16 + lq * 4 + reg;
        int s = Tq[Rr];
        int tq0 = s & 4095, rq0 = (s >> 12) & 1;
        lse_r[(((size_t)(bh * 2 + rq0)) << 12) + tq0] = m_run[mt][reg] + __logf(lr);
      }
    }
  #pragma unroll
  for (int mt = 0; mt < 2; ++mt)
    #pragma unroll
    for (int nto = 0; nto < 4; ++nto)
      #pragma unroll
      for (int reg = 0; reg < 4; ++reg)
        Ps[w * 2304 + (mt * 16 + lq * 4 + reg) * 72 + nto * 16 + l15] =
            f2bf(oacc[mt][nto][reg] * invl[mt][reg]);
  #pragma unroll
  for (int pass = 0; pass < 4; ++pass) {
    int rl = pass * 8 + (lane >> 3);
    int s = Tq[w * 32 + rl];
    int tq0 = s & 4095, rq0 = (s >> 12) & 1;
    uint4 ov = *(const uint4*)&Ps[w * 2304 + rl * 72 + (lane & 7) * 8];
    *(uint4*)(o_r + ((((size_t)(bh * 2 + rq0)) << 12) + tq0) * 64 + (lane & 7) * 8) = ov;
  }
}

// ---------------------------------------------------------------- combine hash rounds
__global__ __launch_bounds__(256) void k_combine(
    const unsigned short* __restrict__ o_r,
    const float* __restrict__ lse_r,
    unsigned short* __restrict__ attn) {
  int idx = blockIdx.x * 256 + threadIdx.x;
  if (idx >= 48 * 4096 * 64) return;
  int f = idx & 63;
  int t = (idx >> 6) & 4095;
  int bh = idx >> 18;
  float l0 = lse_r[((size_t)(bh * 2 + 0) << 12) + t];
  float l1 = lse_r[((size_t)(bh * 2 + 1) << 12) + t];
  float mm = fmaxf(l0, l1);
  float e0 = __expf(l0 - mm), e1 = __expf(l1 - mm);
  float inv = 1.0f / (e0 + e1);
  float o0 = bf2f(o_r[(((size_t)(bh * 2 + 0) << 12) + t) * 64 + f]);
  float o1 = bf2f(o_r[(((size_t)(bh * 2 + 1) << 12) + t) * 64 + f]);
  float res = (e0 * o0 + e1 * o1) * inv;
  int b = bh / 12, hh = bh % 12;
  attn[((size_t)(b * 4096 + t)) * 768 + hh * 64 + f] = f2bf(res);
}

extern "C" void kernel_launch(void* const* d_in, const int* in_sizes, int n_in,
                              void* d_out, int out_size, void* d_ws, size_t ws_size,
                              hipStream_t stream) {
  (void)in_sizes; (void)n_in; (void)out_size; (void)ws_size;
  const void* X    = d_in[0];
  const void* mask = d_in[1];
  const void* Wqk  = d_in[2];
  const void* Wv   = d_in[3];
  const void* rot  = d_in[4];
  const void* Wto  = d_in[5];
  const void* bto  = d_in[6];
  const void* Wo   = d_in[7];
  const void* bo   = d_in[8];

  char* ws = (char*)d_ws;
  int*            flag  = (int*)(ws);
  unsigned short* stick = (unsigned short*)(ws + 256);
  float*          lse_r = (float*)(ws + 786688);
  unsigned short* qk    = (unsigned short*)(ws + 3145984);
  unsigned short* v     = (unsigned short*)(ws + 28311808);
  unsigned short* o_r   = (unsigned short*)(ws + 53477632);
  double*         WrotT = (double*)(ws + 53477632);
  unsigned char*  cls   = (unsigned char*)(ws + 55836928);
  unsigned short* Wqkb  = (unsigned short*)(ws + 56230144);
  unsigned short* Wvb   = (unsigned short*)(ws + 57409792);
  unsigned short* Xb    = (unsigned short*)(ws + 58589440);
  unsigned short* Wtob  = (unsigned short*)(ws + 53477632);
  unsigned short* Wob   = (unsigned short*)(ws + 54657280);
  unsigned short* attn  = v;
  unsigned short* tmp   = qk;

  k_detect<<<1, 64, 0, stream>>>((const unsigned int*)X, flag);
  k_convert<<<49152, 256, 0, stream>>>(X, Xb, 12582912, flag);
  k_convert<<<2304, 256, 0, stream>>>(Wqk, Wqkb, 589824, flag);
  k_convert<<<2304, 256, 0, stream>>>(Wv, Wvb, 589824, flag);
  k_build_wrot<<<1152, 256, 0, stream>>>(Wqk, rot, WrotT, flag);
  k_bucket<<<dim3(128, 4), 256, 0, stream>>>(X, WrotT, cls, flag);
  k_sort<<<48, 1024, 0, stream>>>(cls, stick);
  k_gemm_mfma<<<dim3(128, 6), 256, 0, stream>>>(Xb, Wqkb, nullptr, qk, 1, 0, flag);
  k_gemm_mfma<<<dim3(128, 6), 256, 0, stream>>>(Xb, Wvb,  nullptr, v,  1, 0, flag);
  k_attn_mfma<<<3072, 256, 0, stream>>>(qk, v, stick, mask, o_r, lse_r, flag);
  k_combine<<<49152, 256, 0, stream>>>(o_r, lse_r, attn);
  k_convert<<<2304, 256, 0, stream>>>(Wto, Wtob, 589824, flag);
  k_convert<<<2304, 256, 0, stream>>>(Wo, Wob, 589824, flag);
  k_gemm_mfma<<<dim3(128, 6), 256, 0, stream>>>(attn, Wtob, bto, tmp, 0, 0, flag);
  k_gemm_mfma<<<dim3(128, 6), 256, 0, stream>>>(tmp, Wob, bo, d_out, 0, 1, flag);
}